// Round 2
// baseline (17224.265 us; speedup 1.0000x reference)
//
#include <hip/hip_runtime.h>
#include <hip/hip_bf16.h>

// Problem constants
#define VV 10000
#define DD 512
#define HH 8
#define DH 64
#define DI 2048
#define LL 12
#define BB 4
#define SS 1024
#define TT (BB * SS)   // 4096 tokens

typedef unsigned short u16;
typedef unsigned int u32;

__device__ __forceinline__ float b2f(u16 u) {
    return __uint_as_float(((u32)u) << 16);
}
__device__ __forceinline__ u16 f2b(float f) {
    u32 x = __float_as_uint(f);
    u32 r = (x + 0x7fffu + ((x >> 16) & 1u)) >> 16;
    return (u16)r;
}

// ---------------------------------------------------------------------------
// Dtype probe: ln1_g is all-ones in the reference.
// First 32-bit word: bf16 -> 0x3F803F80 (hi==lo), fp32 -> 0x3F800000.
// flag = 1 if bf16, 0 if fp32.
// ---------------------------------------------------------------------------
__global__ void probe_kernel(const u32* __restrict__ g, int* __restrict__ flag)
{
    u32 w = g[0];
    *flag = ((w >> 16) == (w & 0xFFFFu)) ? 1 : 0;
}

// ---------------------------------------------------------------------------
// Embedding: h[tok,d] = word_emb[data[tok],d] + pos_emb[tok%S, d]
// ---------------------------------------------------------------------------
template<bool BF16IN>
__global__ __launch_bounds__(256) void embed_kernel(
    const int* __restrict__ flagp, int want,
    const int* __restrict__ data, const void* __restrict__ we_,
    const void* __restrict__ pe_, float* __restrict__ h)
{
    if (*flagp != want) return;
    int tok = blockIdx.x;
    int tid = threadIdx.x;
    int idx = data[tok];
    int s = tok & (SS - 1);
    size_t base = (size_t)tok * DD;
    size_t wb = (size_t)idx * DD;
    size_t pb = (size_t)s * DD;
    if (BF16IN) {
        const u16* we = (const u16*)we_;
        const u16* pe = (const u16*)pe_;
        h[base + tid]       = b2f(we[wb + tid])       + b2f(pe[pb + tid]);
        h[base + 256 + tid] = b2f(we[wb + 256 + tid]) + b2f(pe[pb + 256 + tid]);
    } else {
        const float* we = (const float*)we_;
        const float* pe = (const float*)pe_;
        h[base + tid]       = we[wb + tid]       + pe[pb + tid];
        h[base + 256 + tid] = we[wb + 256 + tid] + pe[pb + 256 + tid];
    }
}

// ---------------------------------------------------------------------------
// Tiled GEMM: C[M,N] = A[M,K] (fp32) x W[N,K]^T (bf16 or fp32)  (+bias)(+relu)
// Block computes 64x64 tile, 256 threads, 4x4 per thread.
// EPI: 0 = none, 1 = +bias, 2 = +bias+relu.
// ---------------------------------------------------------------------------
template<int EPI, bool BF16W, bool BF16OUT>
__global__ __launch_bounds__(256) void gemm_nt(
    const int* __restrict__ flagp, int want,
    const float* __restrict__ A, const void* __restrict__ W_,
    const void* __restrict__ bias_, void* __restrict__ Cout,
    int N, int K)
{
    if (*flagp != want) return;

    const int BM = 64, BN = 64, BK = 16;
    __shared__ __align__(16) float As[BK][BM + 4];
    __shared__ __align__(16) float Bs[BK][BN + 4];

    const int tid = threadIdx.x;
    const int tx = tid & 15;         // 0..15 -> N
    const int ty = tid >> 4;         // 0..15 -> M
    const int m0 = blockIdx.y * BM;
    const int n0 = blockIdx.x * BN;
    const int lr = tid >> 2;         // 0..63
    const int lc = (tid & 3) * 4;    // 0,4,8,12

    float acc[4][4] = {};

    for (int k0 = 0; k0 < K; k0 += BK) {
        // A tile: As[k][m]
        float4 a4 = *(const float4*)(A + (size_t)(m0 + lr) * K + k0 + lc);
        As[lc + 0][lr] = a4.x;
        As[lc + 1][lr] = a4.y;
        As[lc + 2][lr] = a4.z;
        As[lc + 3][lr] = a4.w;
        // W tile: Bs[k][n]
        int n = n0 + lr;
        float bx = 0.f, by = 0.f, bz = 0.f, bw = 0.f;
        if (n < N) {
            if (BF16W) {
                ushort4 u = *(const ushort4*)((const u16*)W_ + (size_t)n * K + k0 + lc);
                bx = b2f(u.x); by = b2f(u.y); bz = b2f(u.z); bw = b2f(u.w);
            } else {
                float4 f = *(const float4*)((const float*)W_ + (size_t)n * K + k0 + lc);
                bx = f.x; by = f.y; bz = f.z; bw = f.w;
            }
        }
        Bs[lc + 0][lr] = bx;
        Bs[lc + 1][lr] = by;
        Bs[lc + 2][lr] = bz;
        Bs[lc + 3][lr] = bw;
        __syncthreads();

        #pragma unroll
        for (int kk = 0; kk < BK; ++kk) {
            float4 a = *(const float4*)&As[kk][ty * 4];
            float4 b = *(const float4*)&Bs[kk][tx * 4];
            float am[4] = {a.x, a.y, a.z, a.w};
            float bm[4] = {b.x, b.y, b.z, b.w};
            #pragma unroll
            for (int i = 0; i < 4; ++i)
                #pragma unroll
                for (int j = 0; j < 4; ++j)
                    acc[i][j] += am[i] * bm[j];
        }
        __syncthreads();
    }

    // epilogue
    #pragma unroll
    for (int i = 0; i < 4; ++i) {
        size_t m = (size_t)(m0 + ty * 4 + i);
        #pragma unroll
        for (int j = 0; j < 4; ++j) {
            int n = n0 + tx * 4 + j;
            if (n < N) {
                float v = acc[i][j];
                if (EPI >= 1) {
                    v += BF16W ? b2f(((const u16*)bias_)[n])
                               : ((const float*)bias_)[n];
                }
                if (EPI == 2) v = fmaxf(v, 0.f);
                if (BF16OUT)
                    ((u16*)Cout)[m * N + n] = f2b(v);
                else
                    ((float*)Cout)[m * N + n] = v;
            }
        }
    }
}

// ---------------------------------------------------------------------------
// Fused causal attention, one block per (q, head, batch). All fp32 buffers
// (dtype-independent).
// ---------------------------------------------------------------------------
__global__ __launch_bounds__(256) void attn_kernel(
    const float* __restrict__ q, const float* __restrict__ kv,
    float* __restrict__ av)
{
    const int qi = blockIdx.x;
    const int hh = blockIdx.y;
    const int b  = blockIdx.z;
    const int tid = threadIdx.x;
    const int klen = qi + 1;

    __shared__ float qs[64];
    __shared__ float sc[SS];
    __shared__ float red[256];
    __shared__ float op[256];

    const size_t tokq = (size_t)b * SS + qi;
    if (tid < 64) qs[tid] = q[tokq * 512 + hh * 64 + tid] * 0.125f;
    __syncthreads();

    // scores + local max
    float lmax = -1e30f;
    for (int k = tid; k < klen; k += 256) {
        const float* kr = kv + ((size_t)b * SS + k) * 1024 + hh * 64;
        float s = 0.f;
        #pragma unroll
        for (int d = 0; d < 64; d += 4) {
            float4 kk = *(const float4*)(kr + d);
            s += qs[d] * kk.x + qs[d + 1] * kk.y + qs[d + 2] * kk.z + qs[d + 3] * kk.w;
        }
        sc[k] = s;
        lmax = fmaxf(lmax, s);
    }
    red[tid] = lmax;
    __syncthreads();
    for (int off = 128; off > 0; off >>= 1) {
        if (tid < off) red[tid] = fmaxf(red[tid], red[tid + off]);
        __syncthreads();
    }
    float gmax = red[0];
    __syncthreads();

    // exp + local sum
    float lsum = 0.f;
    for (int k = tid; k < klen; k += 256) {
        float e = __expf(sc[k] - gmax);
        sc[k] = e;
        lsum += e;
    }
    red[tid] = lsum;
    __syncthreads();
    for (int off = 128; off > 0; off >>= 1) {
        if (tid < off) red[tid] += red[tid + off];
        __syncthreads();
    }
    float inv = 1.0f / red[0];
    __syncthreads();

    // P @ V : 4 thread-groups over k, each thread owns one d
    int d = tid & 63, grp = tid >> 6;
    float acc = 0.f;
    for (int k = grp; k < klen; k += 4) {
        acc += sc[k] * kv[((size_t)b * SS + k) * 1024 + 512 + hh * 64 + d];
    }
    op[tid] = acc;
    __syncthreads();
    if (tid < 64) {
        float o = (op[tid] + op[tid + 64] + op[tid + 128] + op[tid + 192]) * inv;
        av[tokq * 512 + hh * 64 + tid] = o;
    }
}

// ---------------------------------------------------------------------------
// Fused residual-add + LayerNorm (post-LN): h = LN(h + x) * g + b
// ---------------------------------------------------------------------------
template<bool BF16IN>
__global__ __launch_bounds__(256) void add_ln_kernel(
    const int* __restrict__ flagp, int want,
    float* __restrict__ h, const float* __restrict__ x,
    const void* __restrict__ g_, const void* __restrict__ b_)
{
    if (*flagp != want) return;
    int tok = blockIdx.x, tid = threadIdx.x;
    size_t base = (size_t)tok * DD;
    float v0 = h[base + tid] + x[base + tid];
    float v1 = h[base + 256 + tid] + x[base + 256 + tid];

    __shared__ float rs[256], rq[256];
    rs[tid] = v0 + v1;
    rq[tid] = v0 * v0 + v1 * v1;
    __syncthreads();
    for (int off = 128; off > 0; off >>= 1) {
        if (tid < off) { rs[tid] += rs[tid + off]; rq[tid] += rq[tid + off]; }
        __syncthreads();
    }
    float mean = rs[0] * (1.f / 512.f);
    float var  = rq[0] * (1.f / 512.f) - mean * mean;
    float inv  = rsqrtf(var + 1e-5f);
    float g0, g1v, bb0, bb1;
    if (BF16IN) {
        const u16* g = (const u16*)g_;
        const u16* b = (const u16*)b_;
        g0 = b2f(g[tid]); g1v = b2f(g[256 + tid]);
        bb0 = b2f(b[tid]); bb1 = b2f(b[256 + tid]);
    } else {
        const float* g = (const float*)g_;
        const float* b = (const float*)b_;
        g0 = g[tid]; g1v = g[256 + tid];
        bb0 = b[tid]; bb1 = b[256 + tid];
    }
    h[base + tid]       = (v0 - mean) * inv * g0  + bb0;
    h[base + 256 + tid] = (v1 - mean) * inv * g1v + bb1;
}

// ---------------------------------------------------------------------------
extern "C" void kernel_launch(void* const* d_in, const int* in_sizes, int n_in,
                              void* d_out, int out_size, void* d_ws, size_t ws_size,
                              hipStream_t stream)
{
    const int*  data = (const int*)d_in[0];
    const void* we   = d_in[1];   // word_emb [V, D]
    const void* pe   = d_in[2];   // pos_emb  [MAX_KLEN, D]
    const void* Wq   = d_in[3];   // [L, 512, 512]
    const void* Wkv  = d_in[4];   // [L, 1024, 512]
    const void* Wo   = d_in[5];   // [L, 512, 512]
    const void* g1   = d_in[6];
    const void* bl1  = d_in[7];
    const void* W1   = d_in[8];   // [L, 2048, 512]
    const void* b1   = d_in[9];
    const void* W2   = d_in[10];  // [L, 512, 2048]
    const void* b2   = d_in[11];
    const void* g2   = d_in[12];
    const void* bl2  = d_in[13];
    const void* outb = d_in[14];  // [V]

    int*   flagp = (int*)d_ws;
    float* buf   = (float*)d_ws + 256;      // keep 1 KiB header for flag
    float* h   = buf;                       // T*512
    float* q   = h  + (size_t)TT * 512;     // T*512
    float* kv  = q  + (size_t)TT * 512;     // T*1024
    float* av  = kv + (size_t)TT * 1024;    // T*512
    float* tmp = av + (size_t)TT * 512;     // T*512
    float* ff  = q;                         // reuse q|kv|av region: T*2048

    auto e16 = [](const void* p, size_t e) { return (const void*)((const u16*)p + e); };
    auto e32 = [](const void* p, size_t e) { return (const void*)((const float*)p + e); };

    probe_kernel<<<1, 1, 0, stream>>>((const u32*)g1, flagp);

    embed_kernel<true ><<<TT, 256, 0, stream>>>(flagp, 1, data, we, pe, h);
    embed_kernel<false><<<TT, 256, 0, stream>>>(flagp, 0, data, we, pe, h);

    for (int l = 0; l < LL; ++l) {
        size_t oq = (size_t)l * 512 * 512;
        size_t okv = (size_t)l * 1024 * 512;
        size_t oo = (size_t)l * 512 * 512;
        size_t o1 = (size_t)l * 2048 * 512;
        size_t o2 = (size_t)l * 512 * 2048;

        gemm_nt<0, true , false><<<dim3(8, 64), 256, 0, stream>>>(flagp, 1, h, e16(Wq, oq), nullptr, q, 512, 512);
        gemm_nt<0, false, false><<<dim3(8, 64), 256, 0, stream>>>(flagp, 0, h, e32(Wq, oq), nullptr, q, 512, 512);

        gemm_nt<0, true , false><<<dim3(16, 64), 256, 0, stream>>>(flagp, 1, h, e16(Wkv, okv), nullptr, kv, 1024, 512);
        gemm_nt<0, false, false><<<dim3(16, 64), 256, 0, stream>>>(flagp, 0, h, e32(Wkv, okv), nullptr, kv, 1024, 512);

        attn_kernel<<<dim3(SS, HH, BB), 256, 0, stream>>>(q, kv, av);

        gemm_nt<0, true , false><<<dim3(8, 64), 256, 0, stream>>>(flagp, 1, av, e16(Wo, oo), nullptr, tmp, 512, 512);
        gemm_nt<0, false, false><<<dim3(8, 64), 256, 0, stream>>>(flagp, 0, av, e32(Wo, oo), nullptr, tmp, 512, 512);

        add_ln_kernel<true ><<<TT, 256, 0, stream>>>(flagp, 1, h, tmp, e16(g1, (size_t)l * 512), e16(bl1, (size_t)l * 512));
        add_ln_kernel<false><<<TT, 256, 0, stream>>>(flagp, 0, h, tmp, e32(g1, (size_t)l * 512), e32(bl1, (size_t)l * 512));

        gemm_nt<2, true , false><<<dim3(32, 64), 256, 0, stream>>>(flagp, 1, h, e16(W1, o1), e16(b1, (size_t)l * 2048), ff, 2048, 512);
        gemm_nt<2, false, false><<<dim3(32, 64), 256, 0, stream>>>(flagp, 0, h, e32(W1, o1), e32(b1, (size_t)l * 2048), ff, 2048, 512);

        gemm_nt<1, true , false><<<dim3(8, 64), 256, 0, stream>>>(flagp, 1, ff, e16(W2, o2), e16(b2, (size_t)l * 512), tmp, 512, 2048);
        gemm_nt<1, false, false><<<dim3(8, 64), 256, 0, stream>>>(flagp, 0, ff, e32(W2, o2), e32(b2, (size_t)l * 512), tmp, 512, 2048);

        add_ln_kernel<true ><<<TT, 256, 0, stream>>>(flagp, 1, h, tmp, e16(g2, (size_t)l * 512), e16(bl2, (size_t)l * 512));
        add_ln_kernel<false><<<TT, 256, 0, stream>>>(flagp, 0, h, tmp, e32(g2, (size_t)l * 512), e32(bl2, (size_t)l * 512));
    }

    // logits = h @ word_emb^T + out_b  (out dtype matches input dtype class)
    gemm_nt<1, true , true ><<<dim3((VV + 63) / 64, 64), 256, 0, stream>>>(flagp, 1, h, we, outb, d_out, VV, 512);
    gemm_nt<1, false, false><<<dim3((VV + 63) / 64, 64), 256, 0, stream>>>(flagp, 0, h, we, outb, d_out, VV, 512);
}

// Round 3
// 7440.461 us; speedup vs baseline: 2.3149x; 2.3149x over previous
//
#include <hip/hip_runtime.h>

// Problem constants
#define VV 10000
#define DD 512
#define HH 8
#define DH 64
#define DI 2048
#define LL 12
#define BB 4
#define SS 1024
#define TT (BB * SS)   // 4096 tokens

// Dtype: confirmed fp32 for all float tensors (round-2 probe: bf16
// interpretation NaN'd upstream, fp32 branch passed). Output fp32.

// ---------------------------------------------------------------------------
// Embedding: h[tok,d] = word_emb[data[tok],d] + pos_emb[tok%S, d]
// ---------------------------------------------------------------------------
__global__ __launch_bounds__(256) void embed_kernel(
    const int* __restrict__ data, const float* __restrict__ we,
    const float* __restrict__ pe, float* __restrict__ h)
{
    int tok = blockIdx.x;
    int tid = threadIdx.x;
    int idx = data[tok];
    int s = tok & (SS - 1);
    size_t base = (size_t)tok * DD;
    size_t wb = (size_t)idx * DD;
    size_t pb = (size_t)s * DD;
    h[base + tid]       = we[wb + tid]       + pe[pb + tid];
    h[base + 256 + tid] = we[wb + 256 + tid] + pe[pb + 256 + tid];
}

// ---------------------------------------------------------------------------
// Tiled GEMM: C[M,N] = A[M,K] x W[N,K]^T (+bias)(+relu), all fp32.
// Block computes 64x64 tile, 256 threads, 4x4 per thread.
// EPI: 0 = none, 1 = +bias, 2 = +bias+relu.
// ---------------------------------------------------------------------------
template<int EPI>
__global__ __launch_bounds__(256) void gemm_nt(
    const float* __restrict__ A, const float* __restrict__ W,
    const float* __restrict__ bias, float* __restrict__ C,
    int N, int K)
{
    const int BM = 64, BN = 64, BK = 16;
    __shared__ __align__(16) float As[BK][BM + 4];
    __shared__ __align__(16) float Bs[BK][BN + 4];

    const int tid = threadIdx.x;
    const int tx = tid & 15;         // 0..15 -> N
    const int ty = tid >> 4;         // 0..15 -> M
    const int m0 = blockIdx.y * BM;
    const int n0 = blockIdx.x * BN;
    const int lr = tid >> 2;         // 0..63
    const int lc = (tid & 3) * 4;    // 0,4,8,12

    float acc[4][4] = {};

    for (int k0 = 0; k0 < K; k0 += BK) {
        float4 a4 = *(const float4*)(A + (size_t)(m0 + lr) * K + k0 + lc);
        As[lc + 0][lr] = a4.x;
        As[lc + 1][lr] = a4.y;
        As[lc + 2][lr] = a4.z;
        As[lc + 3][lr] = a4.w;
        int n = n0 + lr;
        float bx = 0.f, by = 0.f, bz = 0.f, bw = 0.f;
        if (n < N) {
            float4 f = *(const float4*)(W + (size_t)n * K + k0 + lc);
            bx = f.x; by = f.y; bz = f.z; bw = f.w;
        }
        Bs[lc + 0][lr] = bx;
        Bs[lc + 1][lr] = by;
        Bs[lc + 2][lr] = bz;
        Bs[lc + 3][lr] = bw;
        __syncthreads();

        #pragma unroll
        for (int kk = 0; kk < BK; ++kk) {
            float4 a = *(const float4*)&As[kk][ty * 4];
            float4 b = *(const float4*)&Bs[kk][tx * 4];
            float am[4] = {a.x, a.y, a.z, a.w};
            float bm[4] = {b.x, b.y, b.z, b.w};
            #pragma unroll
            for (int i = 0; i < 4; ++i)
                #pragma unroll
                for (int j = 0; j < 4; ++j)
                    acc[i][j] += am[i] * bm[j];
        }
        __syncthreads();
    }

    #pragma unroll
    for (int i = 0; i < 4; ++i) {
        size_t m = (size_t)(m0 + ty * 4 + i);
        #pragma unroll
        for (int j = 0; j < 4; ++j) {
            int n = n0 + tx * 4 + j;
            if (n < N) {
                float v = acc[i][j];
                if (EPI >= 1) v += bias[n];
                if (EPI == 2) v = fmaxf(v, 0.f);
                C[m * N + n] = v;
            }
        }
    }
}

// ---------------------------------------------------------------------------
// Flash-style causal attention. One block per (q-tile of 64, head, batch).
// q: [tok][512], kv: [tok][1024] (k first, v at +512), av: [tok][512].
// Register-tiled 64x64 matmuls (4x4/thread), online softmax in registers
// with shfl_xor row reductions (row group = 16 lanes sharing ty).
// LDS: QsT (Q transposed, scaled), KPT (K transposed, reused for P^T),
// Vs (natural). 3 x 64x68 fp32 = 52 KiB -> 3 blocks/CU.
// ---------------------------------------------------------------------------
__global__ __launch_bounds__(256) void flash_attn(
    const float* __restrict__ q, const float* __restrict__ kv,
    float* __restrict__ av)
{
    __shared__ __align__(16) float QsT[64][68];
    __shared__ __align__(16) float KPT[64][68];
    __shared__ __align__(16) float Vs [64][68];

    const int qt = 15 - (int)blockIdx.x;   // heavy q-tiles dispatched first
    const int hh = blockIdx.y;
    const int b  = blockIdx.z;
    const int tid = threadIdx.x;
    const int tx = tid & 15;
    const int ty = tid >> 4;
    const int q0 = qt * 64;

    const int srow = tid >> 2;             // 0..63, staging row
    const int sc0  = (tid & 3) * 16;       // staging col offset

    // stage Q transposed + pre-scaled
    {
        const float* src = q + ((size_t)(b * SS + q0 + srow) * 512) + hh * 64 + sc0;
        #pragma unroll
        for (int m = 0; m < 4; ++m) {
            float4 v = *(const float4*)(src + 4 * m);
            QsT[sc0 + 4*m + 0][srow] = v.x * 0.125f;
            QsT[sc0 + 4*m + 1][srow] = v.y * 0.125f;
            QsT[sc0 + 4*m + 2][srow] = v.z * 0.125f;
            QsT[sc0 + 4*m + 3][srow] = v.w * 0.125f;
        }
    }

    float mrun[4], lrun[4], O[4][4];
    #pragma unroll
    for (int ii = 0; ii < 4; ++ii) {
        mrun[ii] = -1e30f; lrun[ii] = 0.f;
        #pragma unroll
        for (int jj = 0; jj < 4; ++jj) O[ii][jj] = 0.f;
    }

    for (int kt = 0; kt <= qt; ++kt) {
        __syncthreads();   // previous-iter KPT/Vs reads done before overwrite
        {
            const float* kp = kv + ((size_t)(b * SS + kt * 64 + srow) * 1024) + hh * 64 + sc0;
            #pragma unroll
            for (int m = 0; m < 4; ++m) {
                float4 kk = *(const float4*)(kp + 4 * m);
                KPT[sc0 + 4*m + 0][srow] = kk.x;
                KPT[sc0 + 4*m + 1][srow] = kk.y;
                KPT[sc0 + 4*m + 2][srow] = kk.z;
                KPT[sc0 + 4*m + 3][srow] = kk.w;
                *(float4*)&Vs[srow][sc0 + 4*m] = *(const float4*)(kp + 512 + 4 * m);
            }
        }
        __syncthreads();

        // S = (Q*scale) K^T : 64x64 tile in 4x4 registers
        float S[4][4] = {};
        #pragma unroll 8
        for (int d = 0; d < 64; ++d) {
            float4 qv = *(const float4*)&QsT[d][ty * 4];
            float4 kk = *(const float4*)&KPT[d][tx * 4];
            float qa[4] = {qv.x, qv.y, qv.z, qv.w};
            float ka[4] = {kk.x, kk.y, kk.z, kk.w};
            #pragma unroll
            for (int ii = 0; ii < 4; ++ii)
                #pragma unroll
                for (int jj = 0; jj < 4; ++jj)
                    S[ii][jj] += qa[ii] * ka[jj];
        }

        // causal mask on the diagonal tile
        if (kt == qt) {
            #pragma unroll
            for (int ii = 0; ii < 4; ++ii)
                #pragma unroll
                for (int jj = 0; jj < 4; ++jj)
                    if (tx * 4 + jj > ty * 4 + ii) S[ii][jj] = -1e30f;
        }

        // online softmax: row stats across the 16 tx-lanes of each row group
        #pragma unroll
        for (int ii = 0; ii < 4; ++ii) {
            float mx = fmaxf(fmaxf(S[ii][0], S[ii][1]), fmaxf(S[ii][2], S[ii][3]));
            mx = fmaxf(mx, __shfl_xor(mx, 1));
            mx = fmaxf(mx, __shfl_xor(mx, 2));
            mx = fmaxf(mx, __shfl_xor(mx, 4));
            mx = fmaxf(mx, __shfl_xor(mx, 8));
            float mn = fmaxf(mrun[ii], mx);
            float alpha = __expf(mrun[ii] - mn);
            mrun[ii] = mn;
            float rs = 0.f;
            #pragma unroll
            for (int jj = 0; jj < 4; ++jj) {
                float p = __expf(S[ii][jj] - mn);
                S[ii][jj] = p;
                rs += p;
            }
            rs += __shfl_xor(rs, 1);
            rs += __shfl_xor(rs, 2);
            rs += __shfl_xor(rs, 4);
            rs += __shfl_xor(rs, 8);
            lrun[ii] = lrun[ii] * alpha + rs;
            #pragma unroll
            for (int jj = 0; jj < 4; ++jj) O[ii][jj] *= alpha;
        }

        __syncthreads();   // all K^T reads done; safe to overwrite with P^T
        #pragma unroll
        for (int jj = 0; jj < 4; ++jj) {
            float4 p4 = make_float4(S[0][jj], S[1][jj], S[2][jj], S[3][jj]);
            *(float4*)&KPT[tx * 4 + jj][ty * 4] = p4;
        }
        __syncthreads();

        // O += P V
        #pragma unroll 8
        for (int k = 0; k < 64; ++k) {
            float4 p4 = *(const float4*)&KPT[k][ty * 4];
            float4 v4 = *(const float4*)&Vs[k][tx * 4];
            float pa[4] = {p4.x, p4.y, p4.z, p4.w};
            float va[4] = {v4.x, v4.y, v4.z, v4.w};
            #pragma unroll
            for (int ii = 0; ii < 4; ++ii)
                #pragma unroll
                for (int jj = 0; jj < 4; ++jj)
                    O[ii][jj] += pa[ii] * va[jj];
        }
    }

    #pragma unroll
    for (int ii = 0; ii < 4; ++ii) {
        float inv = 1.0f / lrun[ii];
        float4 o = make_float4(O[ii][0] * inv, O[ii][1] * inv,
                               O[ii][2] * inv, O[ii][3] * inv);
        *(float4*)(av + ((size_t)(b * SS + q0 + ty * 4 + ii) * 512) + hh * 64 + tx * 4) = o;
    }
}

// ---------------------------------------------------------------------------
// Fused residual-add + LayerNorm (post-LN): h = LN(h + x) * g + b
// ---------------------------------------------------------------------------
__global__ __launch_bounds__(256) void add_ln_kernel(
    float* __restrict__ h, const float* __restrict__ x,
    const float* __restrict__ g, const float* __restrict__ bta)
{
    int tok = blockIdx.x, tid = threadIdx.x;
    size_t base = (size_t)tok * DD;
    float v0 = h[base + tid] + x[base + tid];
    float v1 = h[base + 256 + tid] + x[base + 256 + tid];

    __shared__ float rs[256], rq[256];
    rs[tid] = v0 + v1;
    rq[tid] = v0 * v0 + v1 * v1;
    __syncthreads();
    for (int off = 128; off > 0; off >>= 1) {
        if (tid < off) { rs[tid] += rs[tid + off]; rq[tid] += rq[tid + off]; }
        __syncthreads();
    }
    float mean = rs[0] * (1.f / 512.f);
    float var  = rq[0] * (1.f / 512.f) - mean * mean;
    float inv  = rsqrtf(var + 1e-5f);
    h[base + tid]       = (v0 - mean) * inv * g[tid]       + bta[tid];
    h[base + 256 + tid] = (v1 - mean) * inv * g[256 + tid] + bta[256 + tid];
}

// ---------------------------------------------------------------------------
extern "C" void kernel_launch(void* const* d_in, const int* in_sizes, int n_in,
                              void* d_out, int out_size, void* d_ws, size_t ws_size,
                              hipStream_t stream)
{
    const int*   data = (const int*)d_in[0];
    const float* we   = (const float*)d_in[1];   // word_emb [V, D]
    const float* pe   = (const float*)d_in[2];   // pos_emb  [MAX_KLEN, D]
    const float* Wq   = (const float*)d_in[3];   // [L, 512, 512]
    const float* Wkv  = (const float*)d_in[4];   // [L, 1024, 512]
    const float* Wo   = (const float*)d_in[5];   // [L, 512, 512]
    const float* g1   = (const float*)d_in[6];
    const float* bl1  = (const float*)d_in[7];
    const float* W1   = (const float*)d_in[8];   // [L, 2048, 512]
    const float* b1   = (const float*)d_in[9];
    const float* W2   = (const float*)d_in[10];  // [L, 512, 2048]
    const float* b2   = (const float*)d_in[11];
    const float* g2   = (const float*)d_in[12];
    const float* bl2  = (const float*)d_in[13];
    const float* outb = (const float*)d_in[14];  // [V]
    float* out = (float*)d_out;

    float* ws  = (float*)d_ws;
    float* h   = ws;                        // T*512
    float* q   = h  + (size_t)TT * 512;     // T*512
    float* kv  = q  + (size_t)TT * 512;     // T*1024
    float* av  = kv + (size_t)TT * 1024;    // T*512
    float* tmp = av + (size_t)TT * 512;     // T*512
    float* ff  = q;                         // reuse q|kv|av region: T*2048

    embed_kernel<<<TT, 256, 0, stream>>>(data, we, pe, h);

    for (int l = 0; l < LL; ++l) {
        const float* wq  = Wq  + (size_t)l * 512 * 512;
        const float* wkv = Wkv + (size_t)l * 1024 * 512;
        const float* wo  = Wo  + (size_t)l * 512 * 512;
        const float* w1  = W1  + (size_t)l * 2048 * 512;
        const float* w2  = W2  + (size_t)l * 512 * 2048;

        gemm_nt<0><<<dim3(8, 64), 256, 0, stream>>>(h, wq, nullptr, q, 512, 512);
        gemm_nt<0><<<dim3(16, 64), 256, 0, stream>>>(h, wkv, nullptr, kv, 1024, 512);
        flash_attn<<<dim3(16, HH, BB), 256, 0, stream>>>(q, kv, av);
        gemm_nt<0><<<dim3(8, 64), 256, 0, stream>>>(av, wo, nullptr, tmp, 512, 512);
        add_ln_kernel<<<TT, 256, 0, stream>>>(h, tmp, g1 + l * 512, bl1 + l * 512);
        gemm_nt<2><<<dim3(32, 64), 256, 0, stream>>>(h, w1, b1 + l * 2048, ff, 2048, 512);
        gemm_nt<1><<<dim3(8, 64), 256, 0, stream>>>(ff, w2, b2 + l * 512, tmp, 512, 2048);
        add_ln_kernel<<<TT, 256, 0, stream>>>(h, tmp, g2 + l * 512, bl2 + l * 512);
    }

    // logits = h @ word_emb^T + out_b  -> fp32 out [B,S,V]
    gemm_nt<1><<<dim3((VV + 63) / 64, 64), 256, 0, stream>>>(h, we, outb, out, VV, 512);
}